// Round 2
// baseline (623.905 us; speedup 1.0000x reference)
//
#include <hip/hip_runtime.h>
#include <hip/hip_cooperative_groups.h>

namespace cg = cooperative_groups;

#define IN_F 4096
#define OUT_F 4096
#define BATCH 16384

#define NBLK 1024
#define NCHUNK 256                        // NBLK / 4 col-groups
#define ROWS_PER_CHUNK (OUT_F / NCHUNK)   // 16
// ws float layout:
//   [0 .. NCHUNK*IN_F)      partial column sums (chunk-major)
//   [CS_OFF .. CS_OFF+IN_F) final column sums
//   [BIAS_OFF]              bias sum
#define CS_OFF   (NCHUNK * IN_F)
#define BIAS_OFF (CS_OFF + IN_F)

// One cooperative kernel, three phases separated by grid.sync().
// 1024 blocks x 256 threads, 4 blocks/CU co-resident (VGPR<=128, 16KiB LDS).
__global__ __launch_bounds__(256, 4) void fused_kernel(
    const float* __restrict__ x, const float* __restrict__ W,
    const float* __restrict__ bias, float* __restrict__ ws,
    float* __restrict__ out) {
  cg::grid_group grid = cg::this_grid();
  const int tid = threadIdx.x;
  const int bid = blockIdx.x;

  // ---- Phase A: partial column sums of W (row-major [OUT_F, IN_F]) ----
  // bid -> (colgroup 0..3, chunk 0..255); 16 rows per chunk; plain stores.
  {
    int colgroup = bid & 3;
    int chunk    = bid >> 2;
    int col4     = colgroup * 256 + tid;          // 0..1023 float4 cols
    int row0     = chunk * ROWS_PER_CHUNK;
    const float4* W4 = (const float4*)W;
    float4 acc = make_float4(0.f, 0.f, 0.f, 0.f);
    #pragma unroll
    for (int r = 0; r < ROWS_PER_CHUNK; ++r) {
      float4 v = W4[(size_t)(row0 + r) * (IN_F / 4) + col4];
      acc.x += v.x; acc.y += v.y; acc.z += v.z; acc.w += v.w;
    }
    ((float4*)ws)[(size_t)chunk * (IN_F / 4) + col4] = acc;
  }

  grid.sync();

  // ---- Phase B: reduce NCHUNK partials per column + bias sum ----
  if (bid < 16) {
    int c = bid * 256 + tid;                      // scalar column 0..4095
    float s = 0.f;
    #pragma unroll 8
    for (int k = 0; k < NCHUNK; ++k) s += ws[(size_t)k * IN_F + c];
    ws[CS_OFF + c] = s;
  } else if (bid == 16 && tid < 64) {
    float b = 0.f;
    #pragma unroll
    for (int i = 0; i < OUT_F / 64; ++i) b += bias[tid + i * 64];
    #pragma unroll
    for (int off = 32; off > 0; off >>= 1) b += __shfl_down(b, off);
    if (tid == 0) ws[BIAS_OFF] = b;
  }

  grid.sync();

  // ---- Phase C: out[row] = dot(x[row,:], cs) + bias_sum ----
  // Stage cs into LDS once per block; 16 rows per block (4 waves x 4 rows).
  __shared__ float4 sw[IN_F / 4];                 // 16 KiB
  __shared__ float sbias;
  {
    const float4* cs4 = (const float4*)(ws + CS_OFF);
    #pragma unroll
    for (int i = 0; i < 4; ++i) sw[tid + i * 256] = cs4[tid + i * 256];
    if (tid == 0) sbias = ws[BIAS_OFF];
  }
  __syncthreads();

  int wave = tid >> 6;
  int lane = tid & 63;
  #pragma unroll
  for (int r = 0; r < 4; ++r) {
    int row = bid * 16 + r * 4 + wave;
    const float4* xr = (const float4*)(x + (size_t)row * IN_F);
    float acc = 0.f;
    #pragma unroll
    for (int it = 0; it < 16; ++it) {
      float4 xv = xr[it * 64 + lane];
      float4 wv = sw[it * 64 + lane];
      acc += xv.x * wv.x + xv.y * wv.y + xv.z * wv.z + xv.w * wv.w;
    }
    #pragma unroll
    for (int off = 32; off > 0; off >>= 1) acc += __shfl_down(acc, off);
    if (lane == 0) out[row] = acc + sbias;
  }
}

// -------- Fallback path (plain launches) in case cooperative launch fails --
__global__ __launch_bounds__(256) void colsum_part(
    const float* __restrict__ W, float* __restrict__ ws) {
  int colgroup = blockIdx.x & 3;
  int chunk    = blockIdx.x >> 2;
  int col4     = colgroup * 256 + threadIdx.x;
  int row0     = chunk * ROWS_PER_CHUNK;
  const float4* W4 = (const float4*)W;
  float4 acc = make_float4(0.f, 0.f, 0.f, 0.f);
  #pragma unroll
  for (int r = 0; r < ROWS_PER_CHUNK; ++r) {
    float4 v = W4[(size_t)(row0 + r) * (IN_F / 4) + col4];
    acc.x += v.x; acc.y += v.y; acc.z += v.z; acc.w += v.w;
  }
  ((float4*)ws)[(size_t)chunk * (IN_F / 4) + col4] = acc;
}

__global__ __launch_bounds__(256) void colsum_reduce(
    const float* __restrict__ bias, float* __restrict__ ws) {
  if (blockIdx.x < 16) {
    int c = blockIdx.x * 256 + threadIdx.x;
    float s = 0.f;
    #pragma unroll 8
    for (int k = 0; k < NCHUNK; ++k) s += ws[(size_t)k * IN_F + c];
    ws[CS_OFF + c] = s;
  } else if (threadIdx.x < 64) {
    float b = 0.f;
    #pragma unroll
    for (int i = 0; i < OUT_F / 64; ++i) b += bias[threadIdx.x + i * 64];
    #pragma unroll
    for (int off = 32; off > 0; off >>= 1) b += __shfl_down(b, off);
    if (threadIdx.x == 0) ws[BIAS_OFF] = b;
  }
}

__global__ __launch_bounds__(256) void rowdot_kernel(
    const float* __restrict__ x, const float* __restrict__ ws,
    float* __restrict__ out) {
  int wave = threadIdx.x >> 6;
  int lane = threadIdx.x & 63;
  int row  = blockIdx.x * 4 + wave;
  const float4* xr  = (const float4*)(x + (size_t)row * IN_F);
  const float4* cs4 = (const float4*)(ws + CS_OFF);
  float acc = 0.f;
  #pragma unroll
  for (int it = 0; it < 16; ++it) {
    float4 xv = xr[it * 64 + lane];
    float4 wv = cs4[it * 64 + lane];
    acc += xv.x * wv.x + xv.y * wv.y + xv.z * wv.z + xv.w * wv.w;
  }
  #pragma unroll
  for (int off = 32; off > 0; off >>= 1) acc += __shfl_down(acc, off);
  if (lane == 0) out[row] = acc + ws[BIAS_OFF];
}

extern "C" void kernel_launch(void* const* d_in, const int* in_sizes, int n_in,
                              void* d_out, int out_size, void* d_ws, size_t ws_size,
                              hipStream_t stream) {
  const float* x    = (const float*)d_in[0];
  const float* W    = (const float*)d_in[1];
  const float* bias = (const float*)d_in[2];
  float* out = (float*)d_out;
  float* ws  = (float*)d_ws;

  void* args[] = {(void*)&x, (void*)&W, (void*)&bias, (void*)&ws, (void*)&out};
  hipError_t err = hipLaunchCooperativeKernel(
      reinterpret_cast<void*>(fused_kernel), dim3(NBLK), dim3(256), args, 0,
      stream);
  if (err != hipSuccess) {
    // Fallback: three plain launches (stream-ordered).
    colsum_part<<<dim3(NBLK), 256, 0, stream>>>(W, ws);
    colsum_reduce<<<17, 256, 0, stream>>>(bias, ws);
    rowdot_kernel<<<BATCH / 4, 256, 0, stream>>>(x, ws, out);
  }
}

// Round 4
// 372.538 us; speedup vs baseline: 1.6747x; 1.6747x over previous
//
#include <hip/hip_runtime.h>

#define IN_F 4096
#define OUT_F 4096
#define BATCH 16384

// Native 4-float vector for nontemporal builtins (same layout as float4).
typedef float floatx4 __attribute__((ext_vector_type(4)));

// Partial-sum decomposition: NCHUNK row-chunks, no atomics, no zero-init.
#define NCHUNK 64
#define ROWS_PER_CHUNK (OUT_F / NCHUNK)   // 64
#define PART_F4 (IN_F / 4)                // 1024 float4 columns
// ws float layout:
//   [0 .. NCHUNK*IN_F)      partial column sums (chunk-major)
//   [CS_OFF .. CS_OFF+IN_F) final column sums
//   [BIAS_OFF]              bias sum
#define CS_OFF   (NCHUNK * IN_F)
#define BIAS_OFF (CS_OFF + IN_F)

// Kernel A: partial column sums of W (row-major [OUT_F, IN_F]).
// grid = (4, NCHUNK), block = 256. Thread owns one float4 column group;
// blockIdx.y owns a 64-row chunk. Plain stores to disjoint slots.
// W is read-once: nontemporal loads keep it from thrashing L2.
__global__ __launch_bounds__(256) void colsum_part(
    const float* __restrict__ W, float* __restrict__ ws) {
  int col4 = blockIdx.x * 256 + threadIdx.x;   // 0..1023
  int row0 = blockIdx.y * ROWS_PER_CHUNK;
  const floatx4* W4 = (const floatx4*)W;

  floatx4 acc = (floatx4)(0.f);
  #pragma unroll 8
  for (int r = 0; r < ROWS_PER_CHUNK; ++r) {
    floatx4 v = __builtin_nontemporal_load(&W4[(size_t)(row0 + r) * PART_F4 + col4]);
    acc += v;
  }
  ((floatx4*)ws)[(size_t)blockIdx.y * PART_F4 + col4] = acc;  // cached: re-read soon
}

// Kernel B: reduce NCHUNK partials per column + bias sum.
// grid = 5, block = 256. Blocks 0..3: float4 columns (1 MiB from L2).
// Block 4, wave 0: bias reduction.
__global__ __launch_bounds__(256) void colsum_reduce(
    const float* __restrict__ bias, float* __restrict__ ws) {
  if (blockIdx.x < 4) {
    int col4 = blockIdx.x * 256 + threadIdx.x;  // 0..1023
    const floatx4* p4 = (const floatx4*)ws;
    floatx4 acc = (floatx4)(0.f);
    #pragma unroll 8
    for (int k = 0; k < NCHUNK; ++k) {
      acc += p4[(size_t)k * PART_F4 + col4];
    }
    ((floatx4*)(ws + CS_OFF))[col4] = acc;
  } else if (threadIdx.x < 64) {
    float b = 0.f;
    #pragma unroll
    for (int i = 0; i < OUT_F / 64; ++i) b += bias[threadIdx.x + i * 64];
    #pragma unroll
    for (int off = 32; off > 0; off >>= 1) b += __shfl_down(b, off);
    if (threadIdx.x == 0) ws[BIAS_OFF] = b;
  }
}

// Kernel C: out[row] = dot(x[row,:], colsum) + bias_sum.
// grid = BATCH/4, block = 256 (4 waves, 1 row per wave).
// No LDS: the 16 KiB cs vector is shared by every block and stays
// L1/L2-resident; x streams nontemporally at HBM pace.
__global__ __launch_bounds__(256) void rowdot_kernel(
    const float* __restrict__ x, const float* __restrict__ ws,
    float* __restrict__ out) {
  int wave = threadIdx.x >> 6;
  int lane = threadIdx.x & 63;
  int row  = blockIdx.x * 4 + wave;

  const floatx4* xr  = (const floatx4*)(x + (size_t)row * IN_F);
  const floatx4* cs4 = (const floatx4*)(ws + CS_OFF);

  float acc = 0.f;
  #pragma unroll
  for (int it = 0; it < IN_F / 4 / 64; ++it) {  // 16 iterations
    floatx4 xv = __builtin_nontemporal_load(&xr[it * 64 + lane]);
    floatx4 wv = cs4[it * 64 + lane];
    acc += xv.x * wv.x + xv.y * wv.y + xv.z * wv.z + xv.w * wv.w;
  }
  #pragma unroll
  for (int off = 32; off > 0; off >>= 1) acc += __shfl_down(acc, off);
  if (lane == 0) out[row] = acc + ws[BIAS_OFF];
}

extern "C" void kernel_launch(void* const* d_in, const int* in_sizes, int n_in,
                              void* d_out, int out_size, void* d_ws, size_t ws_size,
                              hipStream_t stream) {
  const float* x    = (const float*)d_in[0];
  const float* W    = (const float*)d_in[1];
  const float* bias = (const float*)d_in[2];
  float* out = (float*)d_out;
  float* ws  = (float*)d_ws;

  // No memset: every ws slot consumed is fully written first (re-poison safe).
  colsum_part<<<dim3(4, NCHUNK), 256, 0, stream>>>(W, ws);
  colsum_reduce<<<5, 256, 0, stream>>>(bias, ws);
  rowdot_kernel<<<BATCH / 4, 256, 0, stream>>>(x, ws, out);
}